// Round 2
// baseline (440.063 us; speedup 1.0000x reference)
//
#include <hip/hip_runtime.h>
#include <math.h>

// SFNAttention on MI355X (gfx950).
// R2: attn -> fixed-max softmax (scores bounded by 8 after qk-norm), LDS-based
//     P redistribution (no shfl), 16 q/wave for 2x occupancy.
//     GEMMs -> global_load_lds width-16 staging.

typedef __bf16 bf16;
typedef bf16 bf16x4 __attribute__((ext_vector_type(4)));
typedef bf16 bf16x8 __attribute__((ext_vector_type(8)));
typedef float f32x4 __attribute__((ext_vector_type(4)));

#define LOG2E 1.4426950408889634f

__device__ __forceinline__ float sfn_f(float x) {
  return fminf(fmaxf(rintf(x + x), -8.0f), 8.0f) * 0.5f;
}

__device__ __forceinline__ void gload16(const bf16* g, bf16* l) {
  __builtin_amdgcn_global_load_lds((const __attribute__((address_space(1))) void*)g,
                                   (__attribute__((address_space(3))) void*)l, 16, 0, 0);
}

// ---------------- prep kernels ----------------

__global__ __launch_bounds__(256) void prep_x_kernel(const float* __restrict__ x,
                                                     bf16* __restrict__ ax) {
  int idx = blockIdx.x * 256 + threadIdx.x;   // 1,048,576 = 4096*1024/4
  int m  = idx >> 8;
  int kc = (idx & 255) << 2;
  const float4 v = *(const float4*)(x + (size_t)m * 1024 + kc);
  bf16 h0 = (bf16)v.x, h1 = (bf16)v.y, h2 = (bf16)v.z, h3 = (bf16)v.w;
  bf16 l0 = (bf16)(v.x - (float)h0), l1 = (bf16)(v.y - (float)h1),
       l2 = (bf16)(v.z - (float)h2), l3 = (bf16)(v.w - (float)h3);
  bf16x4 hv = {h0, h1, h2, h3};
  bf16x4 lv = {l0, l1, l2, l3};
  bf16* p = ax + (size_t)m * 3072 + kc;
  *(bf16x4*)(p)        = hv;
  *(bf16x4*)(p + 1024) = lv;
  *(bf16x4*)(p + 2048) = hv;
}

__global__ __launch_bounds__(256) void prep_w_kernel(const float* __restrict__ Wq,
                                                     const float* __restrict__ Wk,
                                                     const float* __restrict__ Wv,
                                                     bf16* __restrict__ wc) {
  int idx = blockIdx.x * 256 + threadIdx.x;   // 786,432 = 3*1024*1024/4
  int mat = idx >> 18;
  int r   = idx & 262143;
  int n   = r >> 8;
  int kc  = (r & 255) << 2;
  const float* W = (mat == 0) ? Wq : ((mat == 1) ? Wk : Wv);
  const float4 v = *(const float4*)(W + (size_t)n * 1024 + kc);
  bf16 h0 = (bf16)v.x, h1 = (bf16)v.y, h2 = (bf16)v.z, h3 = (bf16)v.w;
  bf16 l0 = (bf16)(v.x - (float)h0), l1 = (bf16)(v.y - (float)h1),
       l2 = (bf16)(v.z - (float)h2), l3 = (bf16)(v.w - (float)h3);
  bf16x4 hv = {h0, h1, h2, h3};
  bf16x4 lv = {l0, l1, l2, l3};
  bf16* p = wc + (size_t)(mat * 1024 + n) * 3072 + kc;
  *(bf16x4*)(p)        = hv;
  *(bf16x4*)(p + 1024) = hv;
  *(bf16x4*)(p + 2048) = lv;
}

__global__ __launch_bounds__(256) void prep_wo_kernel(const float* __restrict__ Wo,
                                                      bf16* __restrict__ wob) {
  int idx = blockIdx.x * 256 + threadIdx.x;   // 262,144 = 1024*1024/4
  const float4 v = *(const float4*)(Wo + (size_t)idx * 4);
  bf16x4 hv = {(bf16)v.x, (bf16)v.y, (bf16)v.z, (bf16)v.w};
  *(bf16x4*)(wob + (size_t)idx * 4) = hv;
}

// ---------------- GEMM (C[m,n] = sum_k A[m,k] * B[n,k]) ----------------
// 128x128 tile, BK=32, 4 waves, 4x4 16x16x32 MFMA frags per wave.
// Staging via global_load_lds width=16 (lane-linear LDS layout).

template <int MODE>
__global__ __launch_bounds__(256, 3) void gemm_bt_kernel(
    const bf16* __restrict__ A, const bf16* __restrict__ Bm, int K,
    const float* __restrict__ b0, const float* __restrict__ b1,
    const float* __restrict__ b2, const float* __restrict__ g0,
    const float* __restrict__ g1, bf16* __restrict__ qn, bf16* __restrict__ kn,
    bf16* __restrict__ vt, float* __restrict__ outf) {
  __shared__ bf16 sA[128 * 32];
  __shared__ bf16 sB[128 * 32];
  const int tid  = threadIdx.x;
  const int wave = tid >> 6;
  const int lane = tid & 63;
  const int lm   = lane & 15;
  const int kg   = lane >> 4;
  const int m0 = blockIdx.y << 7;
  const int n0 = blockIdx.x << 7;
  const int wm = (wave >> 1) << 6;
  const int wn = (wave & 1) << 6;

  f32x4 acc[4][4] = {};

  for (int kt = 0; kt < K; kt += 32) {
    __syncthreads();
#pragma unroll
    for (int j = 0; j < 2; ++j) {
      const int i   = wave * 128 + j * 64 + lane;   // 0..511 chunk id
      const int row = i >> 2;
      const int kc  = (i & 3) << 3;
      gload16(A  + (size_t)(m0 + row) * K + kt + kc, sA + i * 8);
      gload16(Bm + (size_t)(n0 + row) * K + kt + kc, sB + i * 8);
    }
    __syncthreads();
    bf16x8 af[4], bfv[4];
#pragma unroll
    for (int r = 0; r < 4; ++r)
      af[r] = *(const bf16x8*)(sA + (wm + 16 * r + lm) * 32 + kg * 8);
#pragma unroll
    for (int c = 0; c < 4; ++c)
      bfv[c] = *(const bf16x8*)(sB + (wn + 16 * c + lm) * 32 + kg * 8);
#pragma unroll
    for (int r = 0; r < 4; ++r)
#pragma unroll
      for (int c = 0; c < 4; ++c)
        acc[r][c] = __builtin_amdgcn_mfma_f32_16x16x32_bf16(af[r], bfv[c], acc[r][c], 0, 0, 0);
  }

  if (MODE == 0) {
    const int ncb = n0 + wn;        // 64-aligned: one head per wave subtile
    const int mat = ncb >> 10;      // 0=q 1=k 2=v
    const int nin = ncb & 1023;
    const int hh  = nin >> 6;
    const float* bias = (mat == 0) ? b0 : ((mat == 1) ? b1 : b2);
    float bvals[4];
#pragma unroll
    for (int c = 0; c < 4; ++c) bvals[c] = bias[nin + 16 * c + lm];

    if (mat < 2) {
      const float* gain = (mat == 0) ? g0 : g1;
      bf16* dst = (mat == 0) ? qn : kn;
      float gv[4];
#pragma unroll
      for (int c = 0; c < 4; ++c) gv[c] = gain[16 * c + lm];
#pragma unroll
      for (int r = 0; r < 4; ++r) {
        float y[4][4];
        float ss[4] = {0.f, 0.f, 0.f, 0.f};
#pragma unroll
        for (int c = 0; c < 4; ++c)
#pragma unroll
          for (int g = 0; g < 4; ++g) {
            float t = sfn_f(acc[r][c][g] + bvals[c]);
            y[c][g] = t;
            ss[g] += t * t;
          }
#pragma unroll
        for (int g = 0; g < 4; ++g) {
          float s = ss[g];
          s += __shfl_xor(s, 1);
          s += __shfl_xor(s, 2);
          s += __shfl_xor(s, 4);
          s += __shfl_xor(s, 8);
          ss[g] = 1.0f / sqrtf(s * (1.0f / 64.0f) + 1e-6f);
        }
        const int mbase = m0 + wm + 16 * r + 4 * kg;
        const int bb = mbase >> 11;
        const int ll = mbase & 2047;
#pragma unroll
        for (int g = 0; g < 4; ++g) {
          bf16* rowp = dst + ((size_t)(bb * 16 + hh) * 2048 + (ll + g)) * 64;
#pragma unroll
          for (int c = 0; c < 4; ++c)
            rowp[16 * c + lm] = (bf16)(y[c][g] * ss[g] * gv[c]);
        }
      }
    } else {
      // v: sfn only, store transposed [B,H,Dh,L]
#pragma unroll
      for (int r = 0; r < 4; ++r) {
        const int mbase = m0 + wm + 16 * r + 4 * kg;
        const int bb = mbase >> 11;
        const int ll = mbase & 2047;
#pragma unroll
        for (int c = 0; c < 4; ++c) {
          bf16x4 pk;
#pragma unroll
          for (int g = 0; g < 4; ++g)
            pk[g] = (bf16)sfn_f(acc[r][c][g] + bvals[c]);
          *(bf16x4*)(vt + ((size_t)(bb * 16 + hh) * 64 + 16 * c + lm) * 2048 + ll) = pk;
        }
      }
    }
  } else {
    float bvals[4];
#pragma unroll
    for (int c = 0; c < 4; ++c) bvals[c] = b0[n0 + wn + 16 * c + lm];
#pragma unroll
    for (int r = 0; r < 4; ++r) {
      const int mr = m0 + wm + 16 * r + 4 * kg;
#pragma unroll
      for (int c = 0; c < 4; ++c) {
        const int nc = n0 + wn + 16 * c + lm;
#pragma unroll
        for (int g = 0; g < 4; ++g)
          outf[(size_t)(mr + g) * 1024 + nc] = acc[r][c][g] + bvals[c];
      }
    }
  }
}

// ---------------- attention ----------------
// grid (L/64, B*H), 256 thr = 4 waves, each wave owns 16 q rows (q = q0+lm).
// S^T = mfma(K, Q): lane (kg,lm) holds S[k=kt+16rb+4kg+g][q=q0+lm].
// Fixed-max softmax: |s*0.125| <= 8 guaranteed by qk-norm -> p=exp2(fma(s,C1,C2)).
// P redistribution via per-wave LDS tile [16 q][72 k] (pad 72 vs 64 for banks).

__global__ __launch_bounds__(256, 4) void attn_kernel(const bf16* __restrict__ qn,
                                                      const bf16* __restrict__ kn,
                                                      const bf16* __restrict__ vt,
                                                      bf16* __restrict__ ao) {
  __shared__ bf16 sP[4][16][72];
  const int tid  = threadIdx.x;
  const int wave = tid >> 6;
  const int lane = tid & 63;
  const int lm   = lane & 15;
  const int kg   = lane >> 4;
  const int bh   = blockIdx.y;
  const int q0   = (blockIdx.x << 6) + (wave << 4);
  const bf16* qb = qn + (size_t)bh * 2048 * 64;
  const bf16* kb = kn + (size_t)bh * 2048 * 64;
  const bf16* vb = vt + (size_t)bh * 64 * 2048;

  const float C1 = 0.125f * LOG2E;      // fold score scale into exp2 arg
  const float C2 = -8.0f * LOG2E;       // fixed max = 8

  bf16x8 qf[2];
#pragma unroll
  for (int dh = 0; dh < 2; ++dh)
    qf[dh] = *(const bf16x8*)(qb + (size_t)(q0 + lm) * 64 + dh * 32 + kg * 8);

  f32x4 o[4] = {};
  float lrun = 0.f;

  for (int kt = 0; kt < 2048; kt += 64) {
    bf16x8 ka[4][2];
#pragma unroll
    for (int rb = 0; rb < 4; ++rb)
#pragma unroll
      for (int dh = 0; dh < 2; ++dh)
        ka[rb][dh] = *(const bf16x8*)(kb + (size_t)(kt + 16 * rb + lm) * 64 + dh * 32 + kg * 8);

    f32x4 s[4] = {};
#pragma unroll
    for (int rb = 0; rb < 4; ++rb)
#pragma unroll
      for (int dh = 0; dh < 2; ++dh)
        s[rb] = __builtin_amdgcn_mfma_f32_16x16x32_bf16(ka[rb][dh], qf[dh], s[rb], 0, 0, 0);

    // p = exp2(s*0.125*log2e - 8*log2e); accumulate per-lane partial denom
#pragma unroll
    for (int rb = 0; rb < 4; ++rb) {
      bf16x4 pk;
#pragma unroll
      for (int g = 0; g < 4; ++g) {
        float p = __builtin_amdgcn_exp2f(fmaf(s[rb][g], C1, C2));
        lrun += p;
        pk[g] = (bf16)p;
      }
      *(bf16x4*)(&sP[wave][lm][16 * rb + 4 * kg]) = pk;
    }
    asm volatile("s_waitcnt lgkmcnt(0)" ::: "memory");

    bf16x8 pb[2];
#pragma unroll
    for (int kh = 0; kh < 2; ++kh)
      pb[kh] = *(const bf16x8*)(&sP[wave][lm][kh * 32 + kg * 8]);

    bf16x8 va[4][2];
#pragma unroll
    for (int rbd = 0; rbd < 4; ++rbd)
#pragma unroll
      for (int kh = 0; kh < 2; ++kh)
        va[rbd][kh] = *(const bf16x8*)(vb + (size_t)(16 * rbd + lm) * 2048 + kt + kh * 32 + kg * 8);

#pragma unroll
    for (int rbd = 0; rbd < 4; ++rbd)
#pragma unroll
      for (int kh = 0; kh < 2; ++kh)
        o[rbd] = __builtin_amdgcn_mfma_f32_16x16x32_bf16(va[rbd][kh], pb[kh], o[rbd], 0, 0, 0);
  }

  lrun += __shfl_xor(lrun, 16);
  lrun += __shfl_xor(lrun, 32);
  const float inv = 1.0f / lrun;

  const int bb = bh >> 4;
  const int hh = bh & 15;
  bf16* rowp = ao + (size_t)(bb * 2048 + q0 + lm) * 1024 + hh * 64;
#pragma unroll
  for (int rbd = 0; rbd < 4; ++rbd) {
    bf16x4 pk;
#pragma unroll
    for (int g = 0; g < 4; ++g)
      pk[g] = (bf16)(o[rbd][g] * inv);
    *(bf16x4*)(rowp + 16 * rbd + 4 * kg) = pk;
  }
}

// ---------------- launch ----------------

extern "C" void kernel_launch(void* const* d_in, const int* in_sizes, int n_in,
                              void* d_out, int out_size, void* d_ws, size_t ws_size,
                              hipStream_t stream) {
  const float* x  = (const float*)d_in[0];
  const float* Wq = (const float*)d_in[1];
  const float* bq = (const float*)d_in[2];
  const float* Wk = (const float*)d_in[3];
  const float* bk = (const float*)d_in[4];
  const float* Wv = (const float*)d_in[5];
  const float* bv = (const float*)d_in[6];
  const float* Wo = (const float*)d_in[7];
  const float* bo = (const float*)d_in[8];
  const float* gq = (const float*)d_in[9];
  const float* gk = (const float*)d_in[10];
  float* out = (float*)d_out;

  char* ws = (char*)d_ws;
  bf16* ax   = (bf16*)(ws);                    // [4096,3072]  25,165,824
  bf16* wc   = (bf16*)(ws + 25165824);         // [3072,3072]  18,874,368
  bf16* wob  = (bf16*)(ws + 44040192);         // [1024,1024]   2,097,152
  bf16* qn   = (bf16*)(ws + 46137344);         // [B,H,L,Dh]    8,388,608
  bf16* kn   = (bf16*)(ws + 54525952);         // [B,H,L,Dh]    8,388,608
  bf16* vt   = (bf16*)(ws + 62914560);         // [B,H,Dh,L]    8,388,608
  bf16* attn = (bf16*)(ws + 71303168);         // [4096,1024]   8,388,608

  prep_x_kernel<<<dim3(4096), dim3(256), 0, stream>>>(x, ax);
  prep_w_kernel<<<dim3(3072), dim3(256), 0, stream>>>(Wq, Wk, Wv, wc);
  prep_wo_kernel<<<dim3(1024), dim3(256), 0, stream>>>(Wo, wob);

  gemm_bt_kernel<0><<<dim3(24, 32), dim3(256), 0, stream>>>(
      ax, wc, 3072, bq, bk, bv, gq, gk, qn, kn, vt, nullptr);

  attn_kernel<<<dim3(32, 32), dim3(256), 0, stream>>>(qn, kn, vt, attn);

  gemm_bt_kernel<1><<<dim3(8, 32), dim3(256), 0, stream>>>(
      attn, wob, 1024, bo, nullptr, nullptr, nullptr, nullptr,
      nullptr, nullptr, nullptr, out);
}

// Round 3
// 271.930 us; speedup vs baseline: 1.6183x; 1.6183x over previous
//
#include <hip/hip_runtime.h>
#include <math.h>

// SFNAttention on MI355X (gfx950).
// R3: attn rewrite -> 32 q/wave, K/V staged in LDS per block (XOR-swizzled,
//     global_load_lds both-sides pattern), 2-phase prefetch, fixed-max softmax,
//     per-c LDS P roundtrip. XCD-aware block swizzle on attn + GEMMs.

typedef __bf16 bf16;
typedef bf16 bf16x4 __attribute__((ext_vector_type(4)));
typedef bf16 bf16x8 __attribute__((ext_vector_type(8)));
typedef float f32x4 __attribute__((ext_vector_type(4)));

#define LOG2E 1.4426950408889634f

__device__ __forceinline__ float sfn_f(float x) {
  return fminf(fmaxf(rintf(x + x), -8.0f), 8.0f) * 0.5f;
}

__device__ __forceinline__ void gload16(const bf16* g, bf16* l) {
  __builtin_amdgcn_global_load_lds((const __attribute__((address_space(1))) void*)g,
                                   (__attribute__((address_space(3))) void*)l, 16, 0, 0);
}

// ---------------- prep kernels ----------------

__global__ __launch_bounds__(256) void prep_x_kernel(const float* __restrict__ x,
                                                     bf16* __restrict__ ax) {
  int idx = blockIdx.x * 256 + threadIdx.x;   // 1,048,576 = 4096*1024/4
  int m  = idx >> 8;
  int kc = (idx & 255) << 2;
  const float4 v = *(const float4*)(x + (size_t)m * 1024 + kc);
  bf16 h0 = (bf16)v.x, h1 = (bf16)v.y, h2 = (bf16)v.z, h3 = (bf16)v.w;
  bf16 l0 = (bf16)(v.x - (float)h0), l1 = (bf16)(v.y - (float)h1),
       l2 = (bf16)(v.z - (float)h2), l3 = (bf16)(v.w - (float)h3);
  bf16x4 hv = {h0, h1, h2, h3};
  bf16x4 lv = {l0, l1, l2, l3};
  bf16* p = ax + (size_t)m * 3072 + kc;
  *(bf16x4*)(p)        = hv;
  *(bf16x4*)(p + 1024) = lv;
  *(bf16x4*)(p + 2048) = hv;
}

__global__ __launch_bounds__(256) void prep_w_kernel(const float* __restrict__ Wq,
                                                     const float* __restrict__ Wk,
                                                     const float* __restrict__ Wv,
                                                     bf16* __restrict__ wc) {
  int idx = blockIdx.x * 256 + threadIdx.x;   // 786,432 = 3*1024*1024/4
  int mat = idx >> 18;
  int r   = idx & 262143;
  int n   = r >> 8;
  int kc  = (r & 255) << 2;
  const float* W = (mat == 0) ? Wq : ((mat == 1) ? Wk : Wv);
  const float4 v = *(const float4*)(W + (size_t)n * 1024 + kc);
  bf16 h0 = (bf16)v.x, h1 = (bf16)v.y, h2 = (bf16)v.z, h3 = (bf16)v.w;
  bf16 l0 = (bf16)(v.x - (float)h0), l1 = (bf16)(v.y - (float)h1),
       l2 = (bf16)(v.z - (float)h2), l3 = (bf16)(v.w - (float)h3);
  bf16x4 hv = {h0, h1, h2, h3};
  bf16x4 lv = {l0, l1, l2, l3};
  bf16* p = wc + (size_t)(mat * 1024 + n) * 3072 + kc;
  *(bf16x4*)(p)        = hv;
  *(bf16x4*)(p + 1024) = hv;
  *(bf16x4*)(p + 2048) = lv;
}

__global__ __launch_bounds__(256) void prep_wo_kernel(const float* __restrict__ Wo,
                                                      bf16* __restrict__ wob) {
  int idx = blockIdx.x * 256 + threadIdx.x;   // 262,144 = 1024*1024/4
  const float4 v = *(const float4*)(Wo + (size_t)idx * 4);
  bf16x4 hv = {(bf16)v.x, (bf16)v.y, (bf16)v.z, (bf16)v.w};
  *(bf16x4*)(wob + (size_t)idx * 4) = hv;
}

// ---------------- GEMM (C[m,n] = sum_k A[m,k] * B[n,k]) ----------------
// 128x128 tile, BK=32, 4 waves, 4x4 16x16x32 MFMA frags per wave.
// global_load_lds width=16 staging; XCD-aware bijective block swizzle.

template <int MODE>
__global__ __launch_bounds__(256, 3) void gemm_bt_kernel(
    const bf16* __restrict__ A, const bf16* __restrict__ Bm, int K,
    const float* __restrict__ b0, const float* __restrict__ b1,
    const float* __restrict__ b2, const float* __restrict__ g0,
    const float* __restrict__ g1, bf16* __restrict__ qn, bf16* __restrict__ kn,
    bf16* __restrict__ vt, float* __restrict__ outf) {
  __shared__ bf16 sA[128 * 32];
  __shared__ bf16 sB[128 * 32];
  const int tid  = threadIdx.x;
  const int wave = tid >> 6;
  const int lane = tid & 63;
  const int lm   = lane & 15;
  const int kg   = lane >> 4;
  // XCD swizzle: grid is (nbx, 32), nb % 8 == 0
  const int nbx = gridDim.x;
  const int lid = blockIdx.x + nbx * blockIdx.y;
  const int cpx = (nbx << 5) >> 3;
  const int logical = (lid & 7) * cpx + (lid >> 3);
  const int m0 = (logical / nbx) << 7;
  const int n0 = (logical % nbx) << 7;
  const int wm = (wave >> 1) << 6;
  const int wn = (wave & 1) << 6;

  f32x4 acc[4][4] = {};

  for (int kt = 0; kt < K; kt += 32) {
    __syncthreads();
#pragma unroll
    for (int j = 0; j < 2; ++j) {
      const int i   = wave * 128 + j * 64 + lane;   // 0..511 chunk id
      const int row = i >> 2;
      const int kc  = (i & 3) << 3;
      gload16(A  + (size_t)(m0 + row) * K + kt + kc, sA + i * 8);
      gload16(Bm + (size_t)(n0 + row) * K + kt + kc, sB + i * 8);
    }
    __syncthreads();
    bf16x8 af[4], bfv[4];
#pragma unroll
    for (int r = 0; r < 4; ++r)
      af[r] = *(const bf16x8*)(sA + (wm + 16 * r + lm) * 32 + kg * 8);
#pragma unroll
    for (int c = 0; c < 4; ++c)
      bfv[c] = *(const bf16x8*)(sB + (wn + 16 * c + lm) * 32 + kg * 8);
#pragma unroll
    for (int r = 0; r < 4; ++r)
#pragma unroll
      for (int c = 0; c < 4; ++c)
        acc[r][c] = __builtin_amdgcn_mfma_f32_16x16x32_bf16(af[r], bfv[c], acc[r][c], 0, 0, 0);
  }

  if (MODE == 0) {
    const int ncb = n0 + wn;        // 64-aligned: one head per wave subtile
    const int mat = ncb >> 10;      // 0=q 1=k 2=v
    const int nin = ncb & 1023;
    const int hh  = nin >> 6;
    const float* bias = (mat == 0) ? b0 : ((mat == 1) ? b1 : b2);
    float bvals[4];
#pragma unroll
    for (int c = 0; c < 4; ++c) bvals[c] = bias[nin + 16 * c + lm];

    if (mat < 2) {
      const float* gain = (mat == 0) ? g0 : g1;
      bf16* dst = (mat == 0) ? qn : kn;
      float gv[4];
#pragma unroll
      for (int c = 0; c < 4; ++c) gv[c] = gain[16 * c + lm];
#pragma unroll
      for (int r = 0; r < 4; ++r) {
        float y[4][4];
        float ss[4] = {0.f, 0.f, 0.f, 0.f};
#pragma unroll
        for (int c = 0; c < 4; ++c)
#pragma unroll
          for (int g = 0; g < 4; ++g) {
            float t = sfn_f(acc[r][c][g] + bvals[c]);
            y[c][g] = t;
            ss[g] += t * t;
          }
#pragma unroll
        for (int g = 0; g < 4; ++g) {
          float s = ss[g];
          s += __shfl_xor(s, 1);
          s += __shfl_xor(s, 2);
          s += __shfl_xor(s, 4);
          s += __shfl_xor(s, 8);
          ss[g] = 1.0f / sqrtf(s * (1.0f / 64.0f) + 1e-6f);
        }
        const int mbase = m0 + wm + 16 * r + 4 * kg;
        const int bb = mbase >> 11;
        const int ll = mbase & 2047;
#pragma unroll
        for (int g = 0; g < 4; ++g) {
          bf16* rowp = dst + ((size_t)(bb * 16 + hh) * 2048 + (ll + g)) * 64;
#pragma unroll
          for (int c = 0; c < 4; ++c)
            rowp[16 * c + lm] = (bf16)(y[c][g] * ss[g] * gv[c]);
        }
      }
    } else {
      // v: sfn only, store transposed [B,H,Dh,L]
#pragma unroll
      for (int r = 0; r < 4; ++r) {
        const int mbase = m0 + wm + 16 * r + 4 * kg;
        const int bb = mbase >> 11;
        const int ll = mbase & 2047;
#pragma unroll
        for (int c = 0; c < 4; ++c) {
          bf16x4 pk;
#pragma unroll
          for (int g = 0; g < 4; ++g)
            pk[g] = (bf16)sfn_f(acc[r][c][g] + bvals[c]);
          *(bf16x4*)(vt + ((size_t)(bb * 16 + hh) * 64 + 16 * c + lm) * 2048 + ll) = pk;
        }
      }
    }
  } else {
    float bvals[4];
#pragma unroll
    for (int c = 0; c < 4; ++c) bvals[c] = b0[n0 + wn + 16 * c + lm];
#pragma unroll
    for (int r = 0; r < 4; ++r) {
      const int mr = m0 + wm + 16 * r + 4 * kg;
#pragma unroll
      for (int c = 0; c < 4; ++c) {
        const int nc = n0 + wn + 16 * c + lm;
#pragma unroll
        for (int g = 0; g < 4; ++g)
          outf[(size_t)(mr + g) * 1024 + nc] = acc[r][c][g] + bvals[c];
      }
    }
  }
}

// ---------------- attention ----------------
// grid (L/128=16, B*H=32), 256 thr = 4 waves, 32 q/wave (q = q0 + 16c + lm).
// K,V tiles (64x64) staged in LDS per block via global_load_lds, XOR-swizzled
// (linear dest + pre-swizzled global source + swizzled ds_read: rule both-sides).
// 2-phase prefetch: stage(t+1) -> compute(t) -> vmcnt(0) -> barrier.
// Fixed-max softmax (|s|<=8 after qk-norm). Per-c P roundtrip in LDS.

__global__ __launch_bounds__(256, 3) void attn_kernel(const bf16* __restrict__ qn,
                                                      const bf16* __restrict__ kn,
                                                      const bf16* __restrict__ vt,
                                                      bf16* __restrict__ ao) {
  __shared__ bf16 sK[2][64 * 64];
  __shared__ bf16 sV[2][64 * 64];
  __shared__ bf16 sP[4][16 * 72];
  const int tid  = threadIdx.x;
  const int wave = tid >> 6;
  const int lane = tid & 63;
  const int lm   = lane & 15;
  const int kg   = lane >> 4;
  // XCD swizzle: 512 blocks, 64/XCD -> 4 heads per XCD (K/V L2-resident)
  const int lid     = blockIdx.x + (blockIdx.y << 4);
  const int logical = ((lid & 7) << 6) | (lid >> 3);
  const int qblk    = logical & 15;
  const int bh      = logical >> 4;
  const int q0      = (qblk << 7) + (wave << 5);
  const bf16* qb = qn + (size_t)bh * 2048 * 64;
  const bf16* kb = kn + (size_t)bh * 2048 * 64;
  const bf16* vb = vt + (size_t)bh * 64 * 2048;

  const float C1 = 0.125f * LOG2E;
  const float C2 = -8.0f * LOG2E;

  // stage one 64x64 tile pair; each wave: 2 chunks x (K,V) = 4 global_load_lds
  const int srow7 = lane >> 3;             // row & 7 within chunk
  const int scl   = (lane & 7) ^ srow7;    // pre-swizzled 16B column
  auto stage = [&](int buf, int kt) {
#pragma unroll
    for (int j = 0; j < 2; ++j) {
      const int ci  = wave * 2 + j;        // chunk 0..7 (8 rows each)
      const int row = ci * 8 + srow7;
      gload16(kb + (size_t)(kt + row) * 64 + scl * 8, &sK[buf][ci * 512]);
      gload16(vb + (size_t)row * 2048 + kt + scl * 8, &sV[buf][ci * 512]);
    }
  };

  bf16x8 qf[2][2];
#pragma unroll
  for (int c = 0; c < 2; ++c)
#pragma unroll
    for (int dh = 0; dh < 2; ++dh)
      qf[c][dh] = *(const bf16x8*)(qb + (size_t)(q0 + 16 * c + lm) * 64 + dh * 32 + kg * 8);

  f32x4 o[4][2] = {};
  float lrun[2] = {0.f, 0.f};

  stage(0, 0);
  asm volatile("s_waitcnt vmcnt(0)" ::: "memory");
  __syncthreads();

  const int a7 = lm & 7;
  for (int t = 0; t < 32; ++t) {
    const int cur = t & 1;
    if (t < 31) stage(cur ^ 1, (t + 1) * 64);

    // K fragments (swizzled read) + QK^T
    bf16x8 ka[4][2];
#pragma unroll
    for (int rb = 0; rb < 4; ++rb)
#pragma unroll
      for (int dh = 0; dh < 2; ++dh)
        ka[rb][dh] = *(const bf16x8*)(&sK[cur][(16 * rb + lm) * 64 + ((dh * 4 + kg) ^ a7) * 8]);

    f32x4 s[4][2] = {};
#pragma unroll
    for (int rb = 0; rb < 4; ++rb)
#pragma unroll
      for (int c = 0; c < 2; ++c)
#pragma unroll
        for (int dh = 0; dh < 2; ++dh)
          s[rb][c] = __builtin_amdgcn_mfma_f32_16x16x32_bf16(ka[rb][dh], qf[c][dh], s[rb][c], 0, 0, 0);

    // softmax (fixed max) + P roundtrip, per c
    bf16x8 pb[2][2];
#pragma unroll
    for (int c = 0; c < 2; ++c) {
#pragma unroll
      for (int rb = 0; rb < 4; ++rb) {
        bf16x4 pk;
#pragma unroll
        for (int g = 0; g < 4; ++g) {
          float p = __builtin_amdgcn_exp2f(fmaf(s[rb][c][g], C1, C2));
          lrun[c] += p;
          pk[g] = (bf16)p;
        }
        *(bf16x4*)(&sP[wave][lm * 72 + 16 * rb + 4 * kg]) = pk;
      }
      asm volatile("s_waitcnt lgkmcnt(0)" ::: "memory");
#pragma unroll
      for (int kh = 0; kh < 2; ++kh)
        pb[c][kh] = *(const bf16x8*)(&sP[wave][lm * 72 + kh * 32 + kg * 8]);
    }

    // V fragments (swizzled read) + PV
    bf16x8 va[4][2];
#pragma unroll
    for (int rbd = 0; rbd < 4; ++rbd)
#pragma unroll
      for (int kh = 0; kh < 2; ++kh)
        va[rbd][kh] = *(const bf16x8*)(&sV[cur][(16 * rbd + lm) * 64 + ((kh * 4 + kg) ^ a7) * 8]);

#pragma unroll
    for (int rbd = 0; rbd < 4; ++rbd)
#pragma unroll
      for (int c = 0; c < 2; ++c)
#pragma unroll
        for (int kh = 0; kh < 2; ++kh)
          o[rbd][c] = __builtin_amdgcn_mfma_f32_16x16x32_bf16(va[rbd][kh], pb[c][kh], o[rbd][c], 0, 0, 0);

    asm volatile("s_waitcnt vmcnt(0)" ::: "memory");
    __syncthreads();
  }

  const int bb = bh >> 4;
  const int hh = bh & 15;
#pragma unroll
  for (int c = 0; c < 2; ++c) {
    float l = lrun[c];
    l += __shfl_xor(l, 16);
    l += __shfl_xor(l, 32);
    const float inv = 1.0f / l;
    const int q = q0 + 16 * c + lm;
    bf16* rowp = ao + (size_t)(bb * 2048 + q) * 1024 + hh * 64;
#pragma unroll
    for (int rbd = 0; rbd < 4; ++rbd) {
      bf16x4 pk;
#pragma unroll
      for (int g = 0; g < 4; ++g)
        pk[g] = (bf16)(o[rbd][c][g] * inv);
      *(bf16x4*)(rowp + 16 * rbd + 4 * kg) = pk;
    }
  }
}

// ---------------- launch ----------------

extern "C" void kernel_launch(void* const* d_in, const int* in_sizes, int n_in,
                              void* d_out, int out_size, void* d_ws, size_t ws_size,
                              hipStream_t stream) {
  const float* x  = (const float*)d_in[0];
  const float* Wq = (const float*)d_in[1];
  const float* bq = (const float*)d_in[2];
  const float* Wk = (const float*)d_in[3];
  const float* bk = (const float*)d_in[4];
  const float* Wv = (const float*)d_in[5];
  const float* bv = (const float*)d_in[6];
  const float* Wo = (const float*)d_in[7];
  const float* bo = (const float*)d_in[8];
  const float* gq = (const float*)d_in[9];
  const float* gk = (const float*)d_in[10];
  float* out = (float*)d_out;

  char* ws = (char*)d_ws;
  bf16* ax   = (bf16*)(ws);                    // [4096,3072]  25,165,824
  bf16* wc   = (bf16*)(ws + 25165824);         // [3072,3072]  18,874,368
  bf16* wob  = (bf16*)(ws + 44040192);         // [1024,1024]   2,097,152
  bf16* qn   = (bf16*)(ws + 46137344);         // [B,H,L,Dh]    8,388,608
  bf16* kn   = (bf16*)(ws + 54525952);         // [B,H,L,Dh]    8,388,608
  bf16* vt   = (bf16*)(ws + 62914560);         // [B,H,Dh,L]    8,388,608
  bf16* attn = (bf16*)(ws + 71303168);         // [4096,1024]   8,388,608

  prep_x_kernel<<<dim3(4096), dim3(256), 0, stream>>>(x, ax);
  prep_w_kernel<<<dim3(3072), dim3(256), 0, stream>>>(Wq, Wk, Wv, wc);
  prep_wo_kernel<<<dim3(1024), dim3(256), 0, stream>>>(Wo, wob);

  gemm_bt_kernel<0><<<dim3(24, 32), dim3(256), 0, stream>>>(
      ax, wc, 3072, bq, bk, bv, gq, gk, qn, kn, vt, nullptr);

  attn_kernel<<<dim3(16, 32), dim3(256), 0, stream>>>(qn, kn, vt, attn);

  gemm_bt_kernel<1><<<dim3(8, 32), dim3(256), 0, stream>>>(
      attn, wob, 1024, bo, nullptr, nullptr, nullptr, nullptr,
      nullptr, nullptr, nullptr, out);
}

// Round 4
// 260.429 us; speedup vs baseline: 1.6898x; 1.0442x over previous
//
#include <hip/hip_runtime.h>
#include <math.h>

// SFNAttention on MI355X (gfx950).
// R4: QKV GEMM -> 256x256x64 8-phase schedule (T1 XCD swizzle, T2 XOR-swizzle
//     both-sides, T3/T4 counted vmcnt never 0, T5 setprio). Attn -> split K/V
//     staging with counted vmcnt (4/2), dual sP, setprio.

typedef __bf16 bf16;
typedef bf16 bf16x4 __attribute__((ext_vector_type(4)));
typedef bf16 bf16x8 __attribute__((ext_vector_type(8)));
typedef float f32x4 __attribute__((ext_vector_type(4)));

#define LOG2E 1.4426950408889634f
#define MFMA16 __builtin_amdgcn_mfma_f32_16x16x32_bf16
#define S_WAITV(N) asm volatile("s_waitcnt vmcnt(" #N ")" ::: "memory")

__device__ __forceinline__ void bar() {
  asm volatile("" ::: "memory");
  __builtin_amdgcn_s_barrier();
  asm volatile("" ::: "memory");
}

__device__ __forceinline__ float sfn_f(float x) {
  return fminf(fmaxf(rintf(x + x), -8.0f), 8.0f) * 0.5f;
}

__device__ __forceinline__ void gload16(const bf16* g, bf16* l) {
  __builtin_amdgcn_global_load_lds((const __attribute__((address_space(1))) void*)g,
                                   (__attribute__((address_space(3))) void*)l, 16, 0, 0);
}

// ---------------- prep kernels ----------------

__global__ __launch_bounds__(256) void prep_x_kernel(const float* __restrict__ x,
                                                     bf16* __restrict__ ax) {
  int idx = blockIdx.x * 256 + threadIdx.x;   // 1,048,576 = 4096*1024/4
  int m  = idx >> 8;
  int kc = (idx & 255) << 2;
  const float4 v = *(const float4*)(x + (size_t)m * 1024 + kc);
  bf16 h0 = (bf16)v.x, h1 = (bf16)v.y, h2 = (bf16)v.z, h3 = (bf16)v.w;
  bf16 l0 = (bf16)(v.x - (float)h0), l1 = (bf16)(v.y - (float)h1),
       l2 = (bf16)(v.z - (float)h2), l3 = (bf16)(v.w - (float)h3);
  bf16x4 hv = {h0, h1, h2, h3};
  bf16x4 lv = {l0, l1, l2, l3};
  bf16* p = ax + (size_t)m * 3072 + kc;
  *(bf16x4*)(p)        = hv;
  *(bf16x4*)(p + 1024) = lv;
  *(bf16x4*)(p + 2048) = hv;
}

__global__ __launch_bounds__(256) void prep_w_kernel(const float* __restrict__ Wq,
                                                     const float* __restrict__ Wk,
                                                     const float* __restrict__ Wv,
                                                     bf16* __restrict__ wc) {
  int idx = blockIdx.x * 256 + threadIdx.x;   // 786,432 = 3*1024*1024/4
  int mat = idx >> 18;
  int r   = idx & 262143;
  int n   = r >> 8;
  int kc  = (r & 255) << 2;
  const float* W = (mat == 0) ? Wq : ((mat == 1) ? Wk : Wv);
  const float4 v = *(const float4*)(W + (size_t)n * 1024 + kc);
  bf16 h0 = (bf16)v.x, h1 = (bf16)v.y, h2 = (bf16)v.z, h3 = (bf16)v.w;
  bf16 l0 = (bf16)(v.x - (float)h0), l1 = (bf16)(v.y - (float)h1),
       l2 = (bf16)(v.z - (float)h2), l3 = (bf16)(v.w - (float)h3);
  bf16x4 hv = {h0, h1, h2, h3};
  bf16x4 lv = {l0, l1, l2, l3};
  bf16* p = wc + (size_t)(mat * 1024 + n) * 3072 + kc;
  *(bf16x4*)(p)        = hv;
  *(bf16x4*)(p + 1024) = hv;
  *(bf16x4*)(p + 2048) = lv;
}

__global__ __launch_bounds__(256) void prep_wo_kernel(const float* __restrict__ Wo,
                                                      bf16* __restrict__ wob) {
  int idx = blockIdx.x * 256 + threadIdx.x;   // 262,144 = 1024*1024/4
  const float4 v = *(const float4*)(Wo + (size_t)idx * 4);
  bf16x4 hv = {(bf16)v.x, (bf16)v.y, (bf16)v.z, (bf16)v.w};
  *(bf16x4*)(wob + (size_t)idx * 4) = hv;
}

// ---------------- QKV GEMM: 256x256 tile, BK=64, 8-phase ----------------
// C[m,n] = sum_k A[m,k]*Wc[n,k]; M=4096 N=3072 K=3072. 8 waves (2Mx4N), each
// wave computes 128x64 (acc[8][4]). LDS 128KiB: [2 dbuf][A0,A1,B0,B1][128*64].
// XOR swizzle col8^=(row&7) pre-applied on global source, applied on ds_read.
// Phases per K-tile: P0 {rdA r0-3, rdB c0-1 | stage B0(t+1)} MFMA q00
//                    P1 {rdB c2-3          | stage B1(t+1)} MFMA q01
//                    P2 {rdA r4-7          |              } MFMA q11
//                    P3 {stage A0,A1(t+2); vmcnt(4)       } MFMA q10
// Raw s_barrier pairs around each MFMA cluster; vmcnt never 0 in steady state.

__global__ __launch_bounds__(512, 2) void gemm_qkv_kernel(
    const bf16* __restrict__ A, const bf16* __restrict__ Bm,
    const float* __restrict__ b0, const float* __restrict__ b1,
    const float* __restrict__ b2, const float* __restrict__ g0,
    const float* __restrict__ g1, bf16* __restrict__ qn, bf16* __restrict__ kn,
    bf16* __restrict__ vt) {
  constexpr int K = 3072, NT = 48;
  __shared__ bf16 lds[2][4][128 * 64];
  const int tid  = threadIdx.x;
  const int wave = tid >> 6;
  const int lane = tid & 63;
  const int lm   = lane & 15;
  const int kg   = lane >> 4;
  const int wm   = wave >> 2;          // 0..1  (M row of wave)
  const int wn   = wave & 3;           // 0..3  (N col of wave)
  // XCD swizzle: 192 blocks -> 24 consecutive per XCD
  const int lid     = blockIdx.x;
  const int logical = (lid & 7) * 24 + (lid >> 3);
  const int m0 = (logical / 12) << 8;
  const int n0 = (logical % 12) << 8;

  const bf16* Abase = A  + (size_t)m0 * K;
  const bf16* Bbase = Bm + (size_t)n0 * K;

  auto stageHalf = [&](int buf, int half, const bf16* base, int kt) {
#pragma unroll
    for (int j = 0; j < 2; ++j) {
      const int c    = j * 512 + tid;
      const int row  = c >> 3;
      const int col8 = (c & 7) ^ (row & 7);
      gload16(base + (size_t)row * K + kt + col8 * 8, &lds[buf][half][c * 8]);
    }
  };

  f32x4 acc[8][4] = {};
  const int bHalf = 2 + (wn >> 1);
  const int bRow  = (wn & 1) << 6;
  const int sw    = lm & 7;

  // prologue: tile0 (4 halves) + tile1 A halves; wait tile0 (oldest 8)
  stageHalf(0, 0, Abase, 0);
  stageHalf(0, 1, Abase + (size_t)128 * K, 0);
  stageHalf(0, 2, Bbase, 0);
  stageHalf(0, 3, Bbase + (size_t)128 * K, 0);
  stageHalf(1, 0, Abase, 64);
  stageHalf(1, 1, Abase + (size_t)128 * K, 64);
  S_WAITV(4);
  bar();

  for (int t = 0; t < NT; ++t) {
    const int cur = t & 1, nxt = cur ^ 1;
    const int kt1 = (t + 1) << 6;
    bf16x8 a[4][2], p01[2][2], p23[2][2];
    // ---- P0: A r0-3, B c0-1 ; stage B0(t+1)
#pragma unroll
    for (int r = 0; r < 4; ++r)
#pragma unroll
      for (int kk = 0; kk < 2; ++kk)
        a[r][kk] = *(const bf16x8*)&lds[cur][wm][(16 * r + lm) * 64 + (((kk << 2) + kg) ^ sw) * 8];
#pragma unroll
    for (int c = 0; c < 2; ++c)
#pragma unroll
      for (int kk = 0; kk < 2; ++kk)
        p01[c][kk] = *(const bf16x8*)&lds[cur][bHalf][(bRow + 16 * c + lm) * 64 + (((kk << 2) + kg) ^ sw) * 8];
    if (t + 1 < NT) stageHalf(nxt, 2, Bbase, kt1);
    bar();
    __builtin_amdgcn_s_setprio(1);
#pragma unroll
    for (int r = 0; r < 4; ++r)
#pragma unroll
      for (int c = 0; c < 2; ++c)
#pragma unroll
        for (int kk = 0; kk < 2; ++kk)
          acc[r][c] = MFMA16(a[r][kk], p01[c][kk], acc[r][c], 0, 0, 0);
    __builtin_amdgcn_s_setprio(0);
    bar();
    // ---- P1: B c2-3 ; stage B1(t+1)
#pragma unroll
    for (int c = 0; c < 2; ++c)
#pragma unroll
      for (int kk = 0; kk < 2; ++kk)
        p23[c][kk] = *(const bf16x8*)&lds[cur][bHalf][(bRow + 16 * (c + 2) + lm) * 64 + (((kk << 2) + kg) ^ sw) * 8];
    if (t + 1 < NT) stageHalf(nxt, 3, Bbase + (size_t)128 * K, kt1);
    bar();
    __builtin_amdgcn_s_setprio(1);
#pragma unroll
    for (int r = 0; r < 4; ++r)
#pragma unroll
      for (int c = 0; c < 2; ++c)
#pragma unroll
        for (int kk = 0; kk < 2; ++kk)
          acc[r][c + 2] = MFMA16(a[r][kk], p23[c][kk], acc[r][c + 2], 0, 0, 0);
    __builtin_amdgcn_s_setprio(0);
    bar();
    // ---- P2: A r4-7
#pragma unroll
    for (int r = 0; r < 4; ++r)
#pragma unroll
      for (int kk = 0; kk < 2; ++kk)
        a[r][kk] = *(const bf16x8*)&lds[cur][wm][(64 + 16 * r + lm) * 64 + (((kk << 2) + kg) ^ sw) * 8];
    bar();
    __builtin_amdgcn_s_setprio(1);
#pragma unroll
    for (int r = 0; r < 4; ++r)
#pragma unroll
      for (int c = 0; c < 2; ++c)
#pragma unroll
        for (int kk = 0; kk < 2; ++kk)
          acc[4 + r][c + 2] = MFMA16(a[r][kk], p23[c][kk], acc[4 + r][c + 2], 0, 0, 0);
    __builtin_amdgcn_s_setprio(0);
    bar();
    // ---- P3: stage A0,A1(t+2) into cur; counted wait for tile t+1
    if (t + 2 < NT) {
      const int kt2 = (t + 2) << 6;
      stageHalf(cur, 0, Abase, kt2);
      stageHalf(cur, 1, Abase + (size_t)128 * K, kt2);
      S_WAITV(4);
    } else {
      S_WAITV(0);
    }
    bar();
    __builtin_amdgcn_s_setprio(1);
#pragma unroll
    for (int r = 0; r < 4; ++r)
#pragma unroll
      for (int c = 0; c < 2; ++c)
#pragma unroll
        for (int kk = 0; kk < 2; ++kk)
          acc[4 + r][c] = MFMA16(a[r][kk], p01[c][kk], acc[4 + r][c], 0, 0, 0);
    __builtin_amdgcn_s_setprio(0);
    bar();
  }

  // ---- epilogue: bias + sfn (+ qk-norm) ----
  const int ncb = n0 + (wn << 6);      // one head per wave col-slice
  const int mat = ncb >> 10;
  const int nin = ncb & 1023;
  const int hh  = nin >> 6;
  const float* bias = (mat == 0) ? b0 : ((mat == 1) ? b1 : b2);
  float bvals[4];
#pragma unroll
  for (int c = 0; c < 4; ++c) bvals[c] = bias[nin + 16 * c + lm];

  if (mat < 2) {
    const float* gain = (mat == 0) ? g0 : g1;
    bf16* dst = (mat == 0) ? qn : kn;
    float gv[4];
#pragma unroll
    for (int c = 0; c < 4; ++c) gv[c] = gain[16 * c + lm];
#pragma unroll
    for (int r = 0; r < 8; ++r) {
      float y[4][4];
      float ss[4] = {0.f, 0.f, 0.f, 0.f};
#pragma unroll
      for (int c = 0; c < 4; ++c)
#pragma unroll
        for (int g = 0; g < 4; ++g) {
          float tq = sfn_f(acc[r][c][g] + bvals[c]);
          y[c][g] = tq;
          ss[g] += tq * tq;
        }
#pragma unroll
      for (int g = 0; g < 4; ++g) {
        float s = ss[g];
        s += __shfl_xor(s, 1);
        s += __shfl_xor(s, 2);
        s += __shfl_xor(s, 4);
        s += __shfl_xor(s, 8);
        ss[g] = 1.0f / sqrtf(s * (1.0f / 64.0f) + 1e-6f);
      }
      const int mbase = m0 + (wm << 7) + 16 * r + 4 * kg;
      const int bb = mbase >> 11;
      const int ll = mbase & 2047;
#pragma unroll
      for (int g = 0; g < 4; ++g) {
        bf16* rowp = dst + ((size_t)(bb * 16 + hh) * 2048 + (ll + g)) * 64;
#pragma unroll
        for (int c = 0; c < 4; ++c)
          rowp[16 * c + lm] = (bf16)(y[c][g] * ss[g] * gv[c]);
      }
    }
  } else {
    // v: sfn only, store transposed [B,H,Dh,L]
#pragma unroll
    for (int r = 0; r < 8; ++r) {
      const int mbase = m0 + (wm << 7) + 16 * r + 4 * kg;
      const int bb = mbase >> 11;
      const int ll = mbase & 2047;
#pragma unroll
      for (int c = 0; c < 4; ++c) {
        bf16x4 pk;
#pragma unroll
        for (int g = 0; g < 4; ++g)
          pk[g] = (bf16)sfn_f(acc[r][c][g] + bvals[c]);
        *(bf16x4*)(vt + ((size_t)(bb * 16 + hh) * 64 + 16 * c + lm) * 2048 + ll) = pk;
      }
    }
  }
}

// ---------------- O-projection GEMM (128x128, BK=32) ----------------

__global__ __launch_bounds__(256, 3) void gemm_o_kernel(
    const bf16* __restrict__ A, const bf16* __restrict__ Bm, int K,
    const float* __restrict__ b0, float* __restrict__ outf) {
  __shared__ bf16 sA[128 * 32];
  __shared__ bf16 sB[128 * 32];
  const int tid  = threadIdx.x;
  const int wave = tid >> 6;
  const int lane = tid & 63;
  const int lm   = lane & 15;
  const int kg   = lane >> 4;
  const int nbx = gridDim.x;
  const int lid = blockIdx.x + nbx * blockIdx.y;
  const int cpx = (nbx << 5) >> 3;
  const int logical = (lid & 7) * cpx + (lid >> 3);
  const int m0 = (logical / nbx) << 7;
  const int n0 = (logical % nbx) << 7;
  const int wm = (wave >> 1) << 6;
  const int wn = (wave & 1) << 6;

  f32x4 acc[4][4] = {};

  for (int kt = 0; kt < K; kt += 32) {
    __syncthreads();
#pragma unroll
    for (int j = 0; j < 2; ++j) {
      const int i   = wave * 128 + j * 64 + lane;
      const int row = i >> 2;
      const int kc  = (i & 3) << 3;
      gload16(A  + (size_t)(m0 + row) * K + kt + kc, sA + i * 8);
      gload16(Bm + (size_t)(n0 + row) * K + kt + kc, sB + i * 8);
    }
    __syncthreads();
    bf16x8 af[4], bfv[4];
#pragma unroll
    for (int r = 0; r < 4; ++r)
      af[r] = *(const bf16x8*)(sA + (wm + 16 * r + lm) * 32 + kg * 8);
#pragma unroll
    for (int c = 0; c < 4; ++c)
      bfv[c] = *(const bf16x8*)(sB + (wn + 16 * c + lm) * 32 + kg * 8);
#pragma unroll
    for (int r = 0; r < 4; ++r)
#pragma unroll
      for (int c = 0; c < 4; ++c)
        acc[r][c] = MFMA16(af[r], bfv[c], acc[r][c], 0, 0, 0);
  }

  float bvals[4];
#pragma unroll
  for (int c = 0; c < 4; ++c) bvals[c] = b0[n0 + wn + 16 * c + lm];
#pragma unroll
  for (int r = 0; r < 4; ++r) {
    const int mr = m0 + wm + 16 * r + 4 * kg;
#pragma unroll
    for (int c = 0; c < 4; ++c) {
      const int nc = n0 + wn + 16 * c + lm;
#pragma unroll
      for (int g = 0; g < 4; ++g)
        outf[(size_t)(mr + g) * 1024 + nc] = acc[r][c][g] + bvals[c];
    }
  }
}

// ---------------- attention ----------------
// grid (16, 32), 4 waves, 32 q/wave. K/V staged in LDS (XOR both-sides),
// split staging + counted vmcnt: stage K(t+1) at top, V(t+1) after QK^T;
// vmcnt(4) before PV (V(t) landed), vmcnt(2) at bottom (K(t+1) landed).

__global__ __launch_bounds__(256, 3) void attn_kernel(const bf16* __restrict__ qn,
                                                      const bf16* __restrict__ kn,
                                                      const bf16* __restrict__ vt,
                                                      bf16* __restrict__ ao) {
  __shared__ bf16 sK[2][64 * 64];
  __shared__ bf16 sV[2][64 * 64];
  __shared__ bf16 sP[4][2][16 * 72];
  const int tid  = threadIdx.x;
  const int wave = tid >> 6;
  const int lane = tid & 63;
  const int lm   = lane & 15;
  const int kg   = lane >> 4;
  const int lid     = blockIdx.x + (blockIdx.y << 4);
  const int logical = ((lid & 7) << 6) | (lid >> 3);
  const int qblk    = logical & 15;
  const int bh      = logical >> 4;
  const int q0      = (qblk << 7) + (wave << 5);
  const bf16* qb = qn + (size_t)bh * 2048 * 64;
  const bf16* kb = kn + (size_t)bh * 2048 * 64;
  const bf16* vb = vt + (size_t)bh * 64 * 2048;

  const float C1 = 0.125f * LOG2E;
  const float C2 = -8.0f * LOG2E;

  const int srow7 = lane >> 3;
  const int scl   = (lane & 7) ^ srow7;
  auto stageK = [&](int buf, int kt) {
#pragma unroll
    for (int j = 0; j < 2; ++j) {
      const int ci  = wave * 2 + j;
      const int row = ci * 8 + srow7;
      gload16(kb + (size_t)(kt + row) * 64 + scl * 8, &sK[buf][ci * 512]);
    }
  };
  auto stageV = [&](int buf, int kt) {
#pragma unroll
    for (int j = 0; j < 2; ++j) {
      const int ci  = wave * 2 + j;
      const int row = ci * 8 + srow7;
      gload16(vb + (size_t)row * 2048 + kt + scl * 8, &sV[buf][ci * 512]);
    }
  };

  bf16x8 qf[2][2];
#pragma unroll
  for (int c = 0; c < 2; ++c)
#pragma unroll
    for (int dh = 0; dh < 2; ++dh)
      qf[c][dh] = *(const bf16x8*)(qb + (size_t)(q0 + 16 * c + lm) * 64 + dh * 32 + kg * 8);

  f32x4 o[4][2] = {};
  float lrun[2] = {0.f, 0.f};

  stageK(0, 0);
  stageV(0, 0);
  S_WAITV(0);
  bar();

  const int a7 = lm & 7;
  for (int t = 0; t < 32; ++t) {
    const int cur = t & 1, nxt = cur ^ 1;
    const int ktn = (t + 1) << 6;
    if (t < 31) stageK(nxt, ktn);

    bf16x8 ka[4][2];
#pragma unroll
    for (int rb = 0; rb < 4; ++rb)
#pragma unroll
      for (int dh = 0; dh < 2; ++dh)
        ka[rb][dh] = *(const bf16x8*)(&sK[cur][(16 * rb + lm) * 64 + ((dh * 4 + kg) ^ a7) * 8]);

    f32x4 s[4][2] = {};
    __builtin_amdgcn_s_setprio(1);
#pragma unroll
    for (int rb = 0; rb < 4; ++rb)
#pragma unroll
      for (int c = 0; c < 2; ++c)
#pragma unroll
        for (int dh = 0; dh < 2; ++dh)
          s[rb][c] = MFMA16(ka[rb][dh], qf[c][dh], s[rb][c], 0, 0, 0);
    __builtin_amdgcn_s_setprio(0);

    if (t < 31) stageV(nxt, ktn);

    // fixed-max softmax: p = exp2(s*0.125*log2e - 8*log2e)
#pragma unroll
    for (int c = 0; c < 2; ++c)
#pragma unroll
      for (int rb = 0; rb < 4; ++rb) {
        bf16x4 pk;
#pragma unroll
        for (int g = 0; g < 4; ++g) {
          float p = __builtin_amdgcn_exp2f(fmaf(s[rb][c][g], C1, C2));
          lrun[c] += p;
          pk[g] = (bf16)p;
        }
        *(bf16x4*)(&sP[wave][c][lm * 72 + 16 * rb + 4 * kg]) = pk;
      }
    bf16x8 pb[2][2];
#pragma unroll
    for (int c = 0; c < 2; ++c)
#pragma unroll
      for (int kh = 0; kh < 2; ++kh)
        pb[c][kh] = *(const bf16x8*)(&sP[wave][c][lm * 72 + kh * 32 + kg * 8]);

    if (t < 31) { S_WAITV(4); } else { S_WAITV(0); }
    bar();                               // V(t) visible block-wide

    bf16x8 va[4][2];
#pragma unroll
    for (int rbd = 0; rbd < 4; ++rbd)
#pragma unroll
      for (int kh = 0; kh < 2; ++kh)
        va[rbd][kh] = *(const bf16x8*)(&sV[cur][(16 * rbd + lm) * 64 + ((kh * 4 + kg) ^ a7) * 8]);

    __builtin_amdgcn_s_setprio(1);
#pragma unroll
    for (int rbd = 0; rbd < 4; ++rbd)
#pragma unroll
      for (int c = 0; c < 2; ++c)
#pragma unroll
        for (int kh = 0; kh < 2; ++kh)
          o[rbd][c] = MFMA16(va[rbd][kh], pb[c][kh], o[rbd][c], 0, 0, 0);
    __builtin_amdgcn_s_setprio(0);

    if (t < 31) {
      S_WAITV(2);                        // K(t+1) landed; V(t+1) in flight
      bar();
    }
  }

  const int bb = bh >> 4;
  const int hh = bh & 15;
#pragma unroll
  for (int c = 0; c < 2; ++c) {
    float l = lrun[c];
    l += __shfl_xor(l, 16);
    l += __shfl_xor(l, 32);
    const float inv = 1.0f / l;
    const int q = q0 + 16 * c + lm;
    bf16* rowp = ao + (size_t)(bb * 2048 + q) * 1024 + hh * 64;
#pragma unroll
    for (int rbd = 0; rbd < 4; ++rbd) {
      bf16x4 pk;
#pragma unroll
      for (int g = 0; g < 4; ++g)
        pk[g] = (bf16)(o[rbd][c][g] * inv);
      *(bf16x4*)(rowp + 16 * rbd + 4 * kg) = pk;
    }
  }
}

// ---------------- launch ----------------

extern "C" void kernel_launch(void* const* d_in, const int* in_sizes, int n_in,
                              void* d_out, int out_size, void* d_ws, size_t ws_size,
                              hipStream_t stream) {
  const float* x  = (const float*)d_in[0];
  const float* Wq = (const float*)d_in[1];
  const float* bq = (const float*)d_in[2];
  const float* Wk = (const float*)d_in[3];
  const float* bk = (const float*)d_in[4];
  const float* Wv = (const float*)d_in[5];
  const float* bv = (const float*)d_in[6];
  const float* Wo = (const float*)d_in[7];
  const float* bo = (const float*)d_in[8];
  const float* gq = (const float*)d_in[9];
  const float* gk = (const float*)d_in[10];
  float* out = (float*)d_out;

  char* ws = (char*)d_ws;
  bf16* ax   = (bf16*)(ws);                    // [4096,3072]  25,165,824
  bf16* wc   = (bf16*)(ws + 25165824);         // [3072,3072]  18,874,368
  bf16* wob  = (bf16*)(ws + 44040192);         // [1024,1024]   2,097,152
  bf16* qn   = (bf16*)(ws + 46137344);         // [B,H,L,Dh]    8,388,608
  bf16* kn   = (bf16*)(ws + 54525952);         // [B,H,L,Dh]    8,388,608
  bf16* vt   = (bf16*)(ws + 62914560);         // [B,H,Dh,L]    8,388,608
  bf16* attn = (bf16*)(ws + 71303168);         // [4096,1024]   8,388,608

  prep_x_kernel<<<dim3(4096), dim3(256), 0, stream>>>(x, ax);
  prep_w_kernel<<<dim3(3072), dim3(256), 0, stream>>>(Wq, Wk, Wv, wc);
  prep_wo_kernel<<<dim3(1024), dim3(256), 0, stream>>>(Wo, wob);

  gemm_qkv_kernel<<<dim3(192), dim3(512), 0, stream>>>(
      ax, wc, bq, bk, bv, gq, gk, qn, kn, vt);

  attn_kernel<<<dim3(16, 32), dim3(256), 0, stream>>>(qn, kn, vt, attn);

  gemm_o_kernel<<<dim3(8, 32), dim3(256), 0, stream>>>(
      attn, wob, 1024, bo, out);
}

// Round 5
// 247.593 us; speedup vs baseline: 1.7774x; 1.0518x over previous
//
#include <hip/hip_runtime.h>
#include <math.h>

// SFNAttention on MI355X (gfx950).
// R5: QKV GEMM -> 256x192 tile, grid 16x16=256 blocks (full CU coverage),
//     8 waves of 32x192 (3 whole heads/wave -> in-wave qk-norm), 4-phase
//     schedule, deep staging, counted vmcnt. Attn -> cross-tile pipeline:
//     QK(t+1) before PV(t), K triple-buffer (t+3), V double-buffer (t+1),
//     P in registers, 1 barrier + vmcnt(2) per tile.

typedef __bf16 bf16;
typedef bf16 bf16x4 __attribute__((ext_vector_type(4)));
typedef bf16 bf16x8 __attribute__((ext_vector_type(8)));
typedef float f32x4 __attribute__((ext_vector_type(4)));

#define LOG2E 1.4426950408889634f
#define MFMA16 __builtin_amdgcn_mfma_f32_16x16x32_bf16
#define S_WAITV(N) asm volatile("s_waitcnt vmcnt(" #N ")" ::: "memory")

__device__ __forceinline__ void bar() {
  asm volatile("" ::: "memory");
  __builtin_amdgcn_s_barrier();
  asm volatile("" ::: "memory");
}

__device__ __forceinline__ float sfn_f(float x) {
  return fminf(fmaxf(rintf(x + x), -8.0f), 8.0f) * 0.5f;
}

__device__ __forceinline__ void gload16(const bf16* g, bf16* l) {
  __builtin_amdgcn_global_load_lds((const __attribute__((address_space(1))) void*)g,
                                   (__attribute__((address_space(3))) void*)l, 16, 0, 0);
}

// ---------------- prep kernels ----------------

__global__ __launch_bounds__(256) void prep_x_kernel(const float* __restrict__ x,
                                                     bf16* __restrict__ ax) {
  int idx = blockIdx.x * 256 + threadIdx.x;   // 1,048,576 = 4096*1024/4
  int m  = idx >> 8;
  int kc = (idx & 255) << 2;
  const float4 v = *(const float4*)(x + (size_t)m * 1024 + kc);
  bf16 h0 = (bf16)v.x, h1 = (bf16)v.y, h2 = (bf16)v.z, h3 = (bf16)v.w;
  bf16 l0 = (bf16)(v.x - (float)h0), l1 = (bf16)(v.y - (float)h1),
       l2 = (bf16)(v.z - (float)h2), l3 = (bf16)(v.w - (float)h3);
  bf16x4 hv = {h0, h1, h2, h3};
  bf16x4 lv = {l0, l1, l2, l3};
  bf16* p = ax + (size_t)m * 3072 + kc;
  *(bf16x4*)(p)        = hv;
  *(bf16x4*)(p + 1024) = lv;
  *(bf16x4*)(p + 2048) = hv;
}

__global__ __launch_bounds__(256) void prep_w_kernel(const float* __restrict__ Wq,
                                                     const float* __restrict__ Wk,
                                                     const float* __restrict__ Wv,
                                                     bf16* __restrict__ wc) {
  int idx = blockIdx.x * 256 + threadIdx.x;   // 786,432 = 3*1024*1024/4
  int mat = idx >> 18;
  int r   = idx & 262143;
  int n   = r >> 8;
  int kc  = (r & 255) << 2;
  const float* W = (mat == 0) ? Wq : ((mat == 1) ? Wk : Wv);
  const float4 v = *(const float4*)(W + (size_t)n * 1024 + kc);
  bf16 h0 = (bf16)v.x, h1 = (bf16)v.y, h2 = (bf16)v.z, h3 = (bf16)v.w;
  bf16 l0 = (bf16)(v.x - (float)h0), l1 = (bf16)(v.y - (float)h1),
       l2 = (bf16)(v.z - (float)h2), l3 = (bf16)(v.w - (float)h3);
  bf16x4 hv = {h0, h1, h2, h3};
  bf16x4 lv = {l0, l1, l2, l3};
  bf16* p = wc + (size_t)(mat * 1024 + n) * 3072 + kc;
  *(bf16x4*)(p)        = hv;
  *(bf16x4*)(p + 1024) = hv;
  *(bf16x4*)(p + 2048) = lv;
}

__global__ __launch_bounds__(256) void prep_wo_kernel(const float* __restrict__ Wo,
                                                      bf16* __restrict__ wob) {
  int idx = blockIdx.x * 256 + threadIdx.x;   // 262,144 = 1024*1024/4
  const float4 v = *(const float4*)(Wo + (size_t)idx * 4);
  bf16x4 hv = {(bf16)v.x, (bf16)v.y, (bf16)v.z, (bf16)v.w};
  *(bf16x4*)(wob + (size_t)idx * 4) = hv;
}

// ---------------- QKV GEMM: 256x192 tile, BK=64, grid 256 ----------------
// C[m,n] = sum_k A[m,k]*Wc[n,k]; M=4096 N=3072 K=3072. 8 waves as 8x1: wave w
// owns rows 32w..32w+31 x all 192 cols (= 3 whole heads -> in-wave qk-norm).
// LDS per buf: A0(128x64) A1(128x64) B0,B1,B2(64x64 each) = 56KB; dbuf 112KB.
// Phases: P0 {rdA r0,r1 kk0/1 + rdB kk0 c0-5 | stage B0(t+1)} MFMA kk0 c0-5
//         P1 {rdB kk0 c6-11                  | stage B1,B2(t+1)} MFMA kk0 c6-11
//         P2 {rdB kk1 c0-5                   |                } MFMA kk1 c0-5
//         P3 {rdB kk1 c6-11 | stage A(t+2); vmcnt(4)} MFMA kk1 c6-11
// Per-acc-element order kk0 then kk1 per tile: bit-identical to R4.

__global__ __launch_bounds__(512, 2) void gemm_qkv_kernel(
    const bf16* __restrict__ A, const bf16* __restrict__ Bm,
    const float* __restrict__ b0, const float* __restrict__ b1,
    const float* __restrict__ b2, const float* __restrict__ g0,
    const float* __restrict__ g1, bf16* __restrict__ qn, bf16* __restrict__ kn,
    bf16* __restrict__ vt) {
  constexpr int K = 3072, NT = 48;
  __shared__ bf16 lds[2][28672];   // A0@0  A1@8192  B0@16384 B1@20480 B2@24576
  const int tid  = threadIdx.x;
  const int wave = tid >> 6;
  const int lane = tid & 63;
  const int lm   = lane & 15;
  const int kg   = lane >> 4;
  // XCD swizzle: 256 blocks -> 32 consecutive logical per XCD (bijective)
  const int lid     = blockIdx.x;
  const int logical = ((lid & 7) << 5) | (lid >> 3);
  const int m0 = (logical >> 4) << 8;    // 16 m-tiles
  const int n0 = (logical & 15) * 192;   // 16 n-tiles

  auto stageA = [&](int buf, int half, int kt) {
#pragma unroll
    for (int j = 0; j < 2; ++j) {
      const int c    = j * 512 + tid;
      const int row  = c >> 3;
      const int col8 = (c & 7) ^ (row & 7);
      gload16(A + (size_t)(m0 + half * 128 + row) * K + kt + col8 * 8,
              &lds[buf][half * 8192 + c * 8]);
    }
  };
  auto stageB = [&](int buf, int ch, int kt) {
    const int row  = tid >> 3;
    const int col8 = (tid & 7) ^ (row & 7);
    gload16(Bm + (size_t)(n0 + ch * 64 + row) * K + kt + col8 * 8,
            &lds[buf][16384 + ch * 4096 + tid * 8]);
  };

  const int sw    = lm & 7;
  const int arow  = (wave << 5) + lm;     // wave-row base + lm (<256)
  auto rdA = [&](int buf, int r, int kk) -> bf16x8 {
    const int row = arow + 16 * r;        // 0..255
    return *(const bf16x8*)&lds[buf][(row >> 7) * 8192 + (row & 127) * 64 +
                                     (((kk << 2) + kg) ^ sw) * 8];
  };
  auto rdB = [&](int buf, int c, int kk) -> bf16x8 {
    const int col = 16 * c + lm;          // 0..191
    return *(const bf16x8*)&lds[buf][16384 + (col >> 6) * 4096 + (col & 63) * 64 +
                                     (((kk << 2) + kg) ^ sw) * 8];
  };

  f32x4 acc[2][12] = {};

  // prologue: tile0 (A+B) + tile1 A; drain tile0 (7 loads), keep A(1) in flight
  stageA(0, 0, 0); stageA(0, 1, 0);
  stageB(0, 0, 0); stageB(0, 1, 0); stageB(0, 2, 0);
  stageA(1, 0, 64); stageA(1, 1, 64);
  S_WAITV(4);
  bar();

  for (int t = 0; t < NT; ++t) {
    const int cur = t & 1, nxt = cur ^ 1;
    const int kt1 = (t + 1) << 6, kt2 = (t + 2) << 6;
    bf16x8 a[2][2], bv[6];
    // ---- P0
#pragma unroll
    for (int r = 0; r < 2; ++r)
#pragma unroll
      for (int kk = 0; kk < 2; ++kk)
        a[r][kk] = rdA(cur, r, kk);
#pragma unroll
    for (int c = 0; c < 6; ++c) bv[c] = rdB(cur, c, 0);
    if (t + 1 < NT) stageB(nxt, 0, kt1);
    bar();
    __builtin_amdgcn_s_setprio(1);
#pragma unroll
    for (int r = 0; r < 2; ++r)
#pragma unroll
      for (int c = 0; c < 6; ++c)
        acc[r][c] = MFMA16(a[r][0], bv[c], acc[r][c], 0, 0, 0);
    __builtin_amdgcn_s_setprio(0);
    bar();
    // ---- P1
    bf16x8 bw[6];
#pragma unroll
    for (int c = 0; c < 6; ++c) bw[c] = rdB(cur, c + 6, 0);
    if (t + 1 < NT) { stageB(nxt, 1, kt1); stageB(nxt, 2, kt1); }
    bar();
    __builtin_amdgcn_s_setprio(1);
#pragma unroll
    for (int r = 0; r < 2; ++r)
#pragma unroll
      for (int c = 0; c < 6; ++c)
        acc[r][c + 6] = MFMA16(a[r][0], bw[c], acc[r][c + 6], 0, 0, 0);
    __builtin_amdgcn_s_setprio(0);
    bar();
    // ---- P2
    bf16x8 bx[6];
#pragma unroll
    for (int c = 0; c < 6; ++c) bx[c] = rdB(cur, c, 1);
    bar();
    __builtin_amdgcn_s_setprio(1);
#pragma unroll
    for (int r = 0; r < 2; ++r)
#pragma unroll
      for (int c = 0; c < 6; ++c)
        acc[r][c] = MFMA16(a[r][1], bx[c], acc[r][c], 0, 0, 0);
    __builtin_amdgcn_s_setprio(0);
    bar();
    // ---- P3
    bf16x8 by[6];
#pragma unroll
    for (int c = 0; c < 6; ++c) by[c] = rdB(cur, c + 6, 1);
    if (t + 2 < NT) {
      stageA(cur, 0, kt2); stageA(cur, 1, kt2);
      S_WAITV(4);
    } else {
      S_WAITV(0);
    }
    bar();
    __builtin_amdgcn_s_setprio(1);
#pragma unroll
    for (int r = 0; r < 2; ++r)
#pragma unroll
      for (int c = 0; c < 6; ++c)
        acc[r][c + 6] = MFMA16(a[r][1], by[c], acc[r][c + 6], 0, 0, 0);
    __builtin_amdgcn_s_setprio(0);
    bar();
  }

  // ---- epilogue: per head h (3 per wave): bias + sfn (+ qk-norm) ----
#pragma unroll
  for (int h = 0; h < 3; ++h) {
    const int gcol = n0 + (h << 6);       // head-aligned global col base
    const int mat  = gcol >> 10;          // 0=q 1=k 2=v
    const int cb   = gcol & 1023;
    const int hh   = cb >> 6;
    const float* bias = (mat == 0) ? b0 : ((mat == 1) ? b1 : b2);
    float bvals[4];
#pragma unroll
    for (int j = 0; j < 4; ++j) bvals[j] = bias[cb + 16 * j + lm];

    if (mat < 2) {
      const float* gain = (mat == 0) ? g0 : g1;
      bf16* dst = (mat == 0) ? qn : kn;
      float gv[4];
#pragma unroll
      for (int j = 0; j < 4; ++j) gv[j] = gain[16 * j + lm];
#pragma unroll
      for (int r = 0; r < 2; ++r) {
        float y[4][4];
        float ss[4] = {0.f, 0.f, 0.f, 0.f};
#pragma unroll
        for (int j = 0; j < 4; ++j)
#pragma unroll
          for (int g = 0; g < 4; ++g) {
            float tq = sfn_f(acc[r][4 * h + j][g] + bvals[j]);
            y[j][g] = tq;
            ss[g] += tq * tq;
          }
#pragma unroll
        for (int g = 0; g < 4; ++g) {
          float s = ss[g];
          s += __shfl_xor(s, 1);
          s += __shfl_xor(s, 2);
          s += __shfl_xor(s, 4);
          s += __shfl_xor(s, 8);
          ss[g] = 1.0f / sqrtf(s * (1.0f / 64.0f) + 1e-6f);
        }
        const int mbase = m0 + (wave << 5) + 16 * r + 4 * kg;
        const int bb = mbase >> 11;
        const int ll = mbase & 2047;
#pragma unroll
        for (int g = 0; g < 4; ++g) {
          bf16* rowp = dst + ((size_t)(bb * 16 + hh) * 2048 + (ll + g)) * 64;
#pragma unroll
          for (int j = 0; j < 4; ++j)
            rowp[16 * j + lm] = (bf16)(y[j][g] * ss[g] * gv[j]);
        }
      }
    } else {
      // v: sfn only, store transposed [B,H,Dh,L]
#pragma unroll
      for (int r = 0; r < 2; ++r) {
        const int mbase = m0 + (wave << 5) + 16 * r + 4 * kg;
        const int bb = mbase >> 11;
        const int ll = mbase & 2047;
#pragma unroll
        for (int j = 0; j < 4; ++j) {
          bf16x4 pk;
#pragma unroll
          for (int g = 0; g < 4; ++g)
            pk[g] = (bf16)sfn_f(acc[r][4 * h + j][g] + bvals[j]);
          *(bf16x4*)(vt + ((size_t)(bb * 16 + hh) * 64 + 16 * j + lm) * 2048 + ll) = pk;
        }
      }
    }
  }
}

// ---------------- O-projection GEMM (128x128, BK=32) ----------------

__global__ __launch_bounds__(256, 3) void gemm_o_kernel(
    const bf16* __restrict__ A, const bf16* __restrict__ Bm, int K,
    const float* __restrict__ b0, float* __restrict__ outf) {
  __shared__ bf16 sA[128 * 32];
  __shared__ bf16 sB[128 * 32];
  const int tid  = threadIdx.x;
  const int wave = tid >> 6;
  const int lane = tid & 63;
  const int lm   = lane & 15;
  const int kg   = lane >> 4;
  const int nbx = gridDim.x;
  const int lid = blockIdx.x + nbx * blockIdx.y;
  const int cpx = (nbx << 5) >> 3;
  const int logical = (lid & 7) * cpx + (lid >> 3);
  const int m0 = (logical / nbx) << 7;
  const int n0 = (logical % nbx) << 7;
  const int wm = (wave >> 1) << 6;
  const int wn = (wave & 1) << 6;

  f32x4 acc[4][4] = {};

  for (int kt = 0; kt < K; kt += 32) {
    __syncthreads();
#pragma unroll
    for (int j = 0; j < 2; ++j) {
      const int i   = wave * 128 + j * 64 + lane;
      const int row = i >> 2;
      const int kc  = (i & 3) << 3;
      gload16(A  + (size_t)(m0 + row) * K + kt + kc, sA + i * 8);
      gload16(Bm + (size_t)(n0 + row) * K + kt + kc, sB + i * 8);
    }
    __syncthreads();
    bf16x8 af[4], bfv[4];
#pragma unroll
    for (int r = 0; r < 4; ++r)
      af[r] = *(const bf16x8*)(sA + (wm + 16 * r + lm) * 32 + kg * 8);
#pragma unroll
    for (int c = 0; c < 4; ++c)
      bfv[c] = *(const bf16x8*)(sB + (wn + 16 * c + lm) * 32 + kg * 8);
#pragma unroll
    for (int r = 0; r < 4; ++r)
#pragma unroll
      for (int c = 0; c < 4; ++c)
        acc[r][c] = MFMA16(af[r], bfv[c], acc[r][c], 0, 0, 0);
  }

  float bvals[4];
#pragma unroll
  for (int c = 0; c < 4; ++c) bvals[c] = b0[n0 + wn + 16 * c + lm];
#pragma unroll
  for (int r = 0; r < 4; ++r) {
    const int mr = m0 + wm + 16 * r + 4 * kg;
#pragma unroll
    for (int c = 0; c < 4; ++c) {
      const int nc = n0 + wn + 16 * c + lm;
#pragma unroll
      for (int g = 0; g < 4; ++g)
        outf[(size_t)(mr + g) * 1024 + nc] = acc[r][c][g] + bvals[c];
    }
  }
}

// ---------------- attention ----------------
// grid (16, 32), 4 waves, 32 q/wave. Cross-tile pipeline: iter t does
// QK(t+1) then PV(t); P lives in registers across iters. K triple-buffered
// (staged t+3 ahead), V double-buffered (t+1). One barrier + counted
// vmcnt(2) per tile (issue order V then K -> vmcnt(2) leaves K(t+3)).

__global__ __launch_bounds__(256, 3) void attn_kernel(const bf16* __restrict__ qn,
                                                      const bf16* __restrict__ kn,
                                                      const bf16* __restrict__ vt,
                                                      bf16* __restrict__ ao) {
  __shared__ bf16 sK[3][64 * 64];
  __shared__ bf16 sV[2][64 * 64];
  __shared__ bf16 sP[4][16 * 72];
  const int tid  = threadIdx.x;
  const int wave = tid >> 6;
  const int lane = tid & 63;
  const int lm   = lane & 15;
  const int kg   = lane >> 4;
  const int lid     = blockIdx.x + (blockIdx.y << 4);
  const int logical = ((lid & 7) << 6) | (lid >> 3);
  const int qblk    = logical & 15;
  const int bh      = logical >> 4;
  const int q0      = (qblk << 7) + (wave << 5);
  const bf16* qb = qn + (size_t)bh * 2048 * 64;
  const bf16* kb = kn + (size_t)bh * 2048 * 64;
  const bf16* vb = vt + (size_t)bh * 64 * 2048;

  const float C1 = 0.125f * LOG2E;
  const float C2 = -8.0f * LOG2E;

  const int srow7 = lane >> 3;
  const int scl   = (lane & 7) ^ srow7;
  auto stageK = [&](int buf, int kt) {
#pragma unroll
    for (int j = 0; j < 2; ++j) {
      const int ci  = wave * 2 + j;
      const int row = ci * 8 + srow7;
      gload16(kb + (size_t)(kt + row) * 64 + scl * 8, &sK[buf][ci * 512]);
    }
  };
  auto stageV = [&](int buf, int kt) {
#pragma unroll
    for (int j = 0; j < 2; ++j) {
      const int ci  = wave * 2 + j;
      const int row = ci * 8 + srow7;
      gload16(vb + (size_t)row * 2048 + kt + scl * 8, &sV[buf][ci * 512]);
    }
  };

  bf16x8 qf[2][2];
#pragma unroll
  for (int c = 0; c < 2; ++c)
#pragma unroll
    for (int dh = 0; dh < 2; ++dh)
      qf[c][dh] = *(const bf16x8*)(qb + (size_t)(q0 + 16 * c + lm) * 64 + dh * 32 + kg * 8);

  f32x4 o[4][2] = {};
  float lrun[2] = {0.f, 0.f};
  bf16x8 pb[2][2];
  const int a7 = lm & 7;

  // softmax helper pattern is inlined twice (prologue + loop) for clarity
  // prologue: V(0), K(0), K(1); compute P(0) -> pb; stage K(2)
  stageV(0, 0);
  stageK(0, 0);
  stageK(1, 64);
  S_WAITV(0);
  bar();
  {
    bf16x8 ka[4][2];
#pragma unroll
    for (int rb = 0; rb < 4; ++rb)
#pragma unroll
      for (int dh = 0; dh < 2; ++dh)
        ka[rb][dh] = *(const bf16x8*)(&sK[0][(16 * rb + lm) * 64 + ((dh * 4 + kg) ^ a7) * 8]);
    f32x4 s[4][2] = {};
#pragma unroll
    for (int rb = 0; rb < 4; ++rb)
#pragma unroll
      for (int c = 0; c < 2; ++c)
#pragma unroll
        for (int dh = 0; dh < 2; ++dh)
          s[rb][c] = MFMA16(ka[rb][dh], qf[c][dh], s[rb][c], 0, 0, 0);
#pragma unroll
    for (int c = 0; c < 2; ++c) {
#pragma unroll
      for (int rb = 0; rb < 4; ++rb) {
        bf16x4 pk;
#pragma unroll
        for (int g = 0; g < 4; ++g) {
          float p = __builtin_amdgcn_exp2f(fmaf(s[rb][c][g], C1, C2));
          lrun[c] += p;
          pk[g] = (bf16)p;
        }
        *(bf16x4*)(&sP[wave][lm * 72 + 16 * rb + 4 * kg]) = pk;
      }
      asm volatile("s_waitcnt lgkmcnt(0)" ::: "memory");
#pragma unroll
      for (int kh = 0; kh < 2; ++kh)
        pb[c][kh] = *(const bf16x8*)(&sP[wave][lm * 72 + kh * 32 + kg * 8]);
    }
  }
  stageK(2, 128);
  bar();

  for (int t = 0; t < 32; ++t) {
    const int vcur = t & 1;
    if (t + 1 < 32) stageV((t + 1) & 1, (t + 1) << 6);
    if (t + 3 < 32) stageK((t + 3) % 3, (t + 3) << 6);

    // ---- QK^T for tile t+1 (K staged 2 iters ago, drained end of t-1)
    f32x4 s[4][2];
    if (t + 1 < 32) {
      const bf16* kbuf = sK[(t + 1) % 3];
      bf16x8 ka[4][2];
#pragma unroll
      for (int rb = 0; rb < 4; ++rb)
#pragma unroll
        for (int dh = 0; dh < 2; ++dh)
          ka[rb][dh] = *(const bf16x8*)(&kbuf[(16 * rb + lm) * 64 + ((dh * 4 + kg) ^ a7) * 8]);
#pragma unroll
      for (int rb = 0; rb < 4; ++rb)
#pragma unroll
        for (int c = 0; c < 2; ++c)
          s[rb][c] = f32x4{0.f, 0.f, 0.f, 0.f};
      __builtin_amdgcn_s_setprio(1);
#pragma unroll
      for (int rb = 0; rb < 4; ++rb)
#pragma unroll
        for (int c = 0; c < 2; ++c)
#pragma unroll
          for (int dh = 0; dh < 2; ++dh)
            s[rb][c] = MFMA16(ka[rb][dh], qf[c][dh], s[rb][c], 0, 0, 0);
      __builtin_amdgcn_s_setprio(0);
    }

    // ---- PV for tile t (pb from previous iteration)
    {
      bf16x8 va[4][2];
#pragma unroll
      for (int rbd = 0; rbd < 4; ++rbd)
#pragma unroll
        for (int kh = 0; kh < 2; ++kh)
          va[rbd][kh] = *(const bf16x8*)(&sV[vcur][(16 * rbd + lm) * 64 + ((kh * 4 + kg) ^ a7) * 8]);
      __builtin_amdgcn_s_setprio(1);
#pragma unroll
      for (int rbd = 0; rbd < 4; ++rbd)
#pragma unroll
        for (int c = 0; c < 2; ++c)
#pragma unroll
          for (int kh = 0; kh < 2; ++kh)
            o[rbd][c] = MFMA16(va[rbd][kh], pb[c][kh], o[rbd][c], 0, 0, 0);
      __builtin_amdgcn_s_setprio(0);
    }

    // ---- softmax(t+1) -> pb
    if (t + 1 < 32) {
#pragma unroll
      for (int c = 0; c < 2; ++c) {
#pragma unroll
        for (int rb = 0; rb < 4; ++rb) {
          bf16x4 pk;
#pragma unroll
          for (int g = 0; g < 4; ++g) {
            float p = __builtin_amdgcn_exp2f(fmaf(s[rb][c][g], C1, C2));
            lrun[c] += p;
            pk[g] = (bf16)p;
          }
          *(bf16x4*)(&sP[wave][lm * 72 + 16 * rb + 4 * kg]) = pk;
        }
        asm volatile("s_waitcnt lgkmcnt(0)" ::: "memory");
#pragma unroll
        for (int kh = 0; kh < 2; ++kh)
          pb[c][kh] = *(const bf16x8*)(&sP[wave][lm * 72 + kh * 32 + kg * 8]);
      }
    }

    if (t + 3 < 32) { S_WAITV(2); } else { S_WAITV(0); }
    bar();
  }

  const int bb = bh >> 4;
  const int hh = bh & 15;
#pragma unroll
  for (int c = 0; c < 2; ++c) {
    float l = lrun[c];
    l += __shfl_xor(l, 16);
    l += __shfl_xor(l, 32);
    const float inv = 1.0f / l;
    const int q = q0 + 16 * c + lm;
    bf16* rowp = ao + (size_t)(bb * 2048 + q) * 1024 + hh * 64;
#pragma unroll
    for (int rbd = 0; rbd < 4; ++rbd) {
      bf16x4 pk;
#pragma unroll
      for (int g = 0; g < 4; ++g)
        pk[g] = (bf16)(o[rbd][c][g] * inv);
      *(bf16x4*)(rowp + 16 * rbd + 4 * kg) = pk;
    }
  }
}

// ---------------- launch ----------------

extern "C" void kernel_launch(void* const* d_in, const int* in_sizes, int n_in,
                              void* d_out, int out_size, void* d_ws, size_t ws_size,
                              hipStream_t stream) {
  const float* x  = (const float*)d_in[0];
  const float* Wq = (const float*)d_in[1];
  const float* bq = (const float*)d_in[2];
  const float* Wk = (const float*)d_in[3];
  const float* bk = (const float*)d_in[4];
  const float* Wv = (const float*)d_in[5];
  const float* bv = (const float*)d_in[6];
  const float* Wo = (const float*)d_in[7];
  const float* bo = (const float*)d_in[8];
  const float* gq = (const float*)d_in[9];
  const float* gk = (const float*)d_in[10];
  float* out = (float*)d_out;

  char* ws = (char*)d_ws;
  bf16* ax   = (bf16*)(ws);                    // [4096,3072]  25,165,824
  bf16* wc   = (bf16*)(ws + 25165824);         // [3072,3072]  18,874,368
  bf16* wob  = (bf16*)(ws + 44040192);         // [1024,1024]   2,097,152
  bf16* qn   = (bf16*)(ws + 46137344);         // [B,H,L,Dh]    8,388,608
  bf16* kn   = (bf16*)(ws + 54525952);         // [B,H,L,Dh]    8,388,608
  bf16* vt   = (bf16*)(ws + 62914560);         // [B,H,Dh,L]    8,388,608
  bf16* attn = (bf16*)(ws + 71303168);         // [4096,1024]   8,388,608

  prep_x_kernel<<<dim3(4096), dim3(256), 0, stream>>>(x, ax);
  prep_w_kernel<<<dim3(3072), dim3(256), 0, stream>>>(Wq, Wk, Wv, wc);
  prep_wo_kernel<<<dim3(1024), dim3(256), 0, stream>>>(Wo, wob);

  gemm_qkv_kernel<<<dim3(256), dim3(512), 0, stream>>>(
      ax, wc, bq, bk, bv, gq, gk, qn, kn, vt);

  attn_kernel<<<dim3(16, 32), dim3(256), 0, stream>>>(qn, kn, vt, attn);

  gemm_o_kernel<<<dim3(8, 32), dim3(256), 0, stream>>>(
      attn, wob, 1024, bo, out);
}